// Round 3
// baseline (669.504 us; speedup 1.0000x reference)
//
#include <hip/hip_runtime.h>
#include <math.h>

#ifndef M_PI
#define M_PI 3.14159265358979323846
#endif

#define B_DIM 8
#define S_DIM 8
#define T_DIM 4096
#define CIN   128
#define COUT  256
#define KT    9
#define NK    5

typedef __attribute__((ext_vector_type(8)))  short bf16x8;   // 8 bf16 = 4 VGPRs
typedef __attribute__((ext_vector_type(16))) float f32x16;   // 32x32 MFMA accum

__device__ __forceinline__ unsigned short f2bf(float f) {
    union { float f; unsigned u; } v; v.f = f;
    unsigned u = v.u;
    u += 0x7fffu + ((u >> 16) & 1u);        // RNE to bf16
    return (unsigned short)(u >> 16);
}

// ---------------- kernel 1: weff_bf16[s][dt][co][ci] = bf16( sum_k wt[s,dt,k] * coeffs[k][ci][co] )
// [co][ci] layout: a B-fragment (n=lane&31 -> co, k contiguous 8 ci) is a contiguous 16 B run.
struct WtArgs { float wt[S_DIM * KT * NK]; };   // 360 floats

__global__ __launch_bounds__(256) void weights_kernel(
    const float* __restrict__ coeffs, unsigned short* __restrict__ weff, WtArgs args)
{
    const int sdt = blockIdx.x;            // 0..71  (s*9+dt)
    const int ci0 = blockIdx.y * 32;       // 4 ci-chunks
    const int co  = threadIdx.x;           // 0..255
    float w[NK];
#pragma unroll
    for (int k = 0; k < NK; ++k) w[k] = args.wt[sdt * NK + k];

    for (int cc = 0; cc < 32; cc += 8) {
        uint4 pack;
        unsigned short* p = (unsigned short*)&pack;
#pragma unroll
        for (int e = 0; e < 8; ++e) {
            int ci = ci0 + cc + e;
            float acc = 0.f;
#pragma unroll
            for (int k = 0; k < NK; ++k)
                acc += w[k] * coeffs[((size_t)k * CIN + ci) * COUT + co];
            p[e] = f2bf(acc);
        }
        *(uint4*)&weff[((size_t)sdt * COUT + co) * CIN + ci0 + cc] = pack;
    }
}

// ---------------- kernel 2: fused scale-conv + bf16 MFMA time-conv GEMM
// 128t x 128co block, 4 waves as 2x2 quadrants of 64x64, each 2x2 of mfma_32x32x16.
// A window in LDS (staged once, fused 3-tap scale conv); B fragments straight from
// global (L2-resident weff) -> barrier-free K-loop.
#define BM 128
#define BN 128
#define AROWS 136          // BM + KT - 1
#define PITCH 136          // 272 B rows: 16B-aligned; frag-read start banks spread 4*(lane&31)

struct BsArgs { float bs[9]; };   // 3x3 scale basis (constant)

__global__ __launch_bounds__(256, 3) void conv_kernel(
    const float* __restrict__ x, const unsigned short* __restrict__ weff,
    const float* __restrict__ cscale, float* __restrict__ out, BsArgs args)
{
    __shared__ unsigned short As[AROWS * PITCH];   // 37 KB -> 3 blocks/CU

    const int tid  = threadIdx.x;
    const int lane = tid & 63, wave = tid >> 6;
    const int lrow = lane & 31;            // m / n index within 32-tile
    const int khalf = lane >> 5;           // k-half: lane holds k = khalf*8 + j
    const int wr = (wave >> 1) * 64;       // wave row quadrant
    const int wc = (wave & 1) * 64;        // wave col quadrant

    const int t0      = blockIdx.x * BM;
    const int co_base = blockIdx.y * BN;
    const int bsix    = blockIdx.z;        // b*8 + s
    const int b = bsix >> 3, s = bsix & 7;
    const int sm = (s > 0) ? s - 1 : 0;
    const int sp = (s < 7) ? s + 1 : 7;

    // w_scale = basis @ coeffs_scale (coeffs_scale is device data)
    const float c0 = cscale[0], c1 = cscale[1], c2 = cscale[2];
    const float w0 = args.bs[0]*c0 + args.bs[1]*c1 + args.bs[2]*c2;
    const float w1 = args.bs[3]*c0 + args.bs[4]*c1 + args.bs[5]*c2;
    const float w2 = args.bs[6]*c0 + args.bs[7]*c1 + args.bs[8]*c2;

    const float* x0 = x + (size_t)(b * S_DIM + sm) * T_DIM * CIN;
    const float* x1 = x + (size_t)(b * S_DIM + s ) * T_DIM * CIN;
    const float* x2 = x + (size_t)(b * S_DIM + sp) * T_DIM * CIN;

    // ---- stage A window once: rows t0-4 .. t0+131, fused 3-tap scale conv, fp32->bf16
    for (int idx = tid; idx < AROWS * 32; idx += 256) {
        int row = idx >> 5;
        int c4  = (idx & 31) << 2;
        int tt  = t0 - 4 + row;
        ushort4 v = make_ushort4(0, 0, 0, 0);
        if (tt >= 0 && tt < T_DIM) {
            size_t off = (size_t)tt * CIN + c4;
            float4 a  = *(const float4*)(x0 + off);
            float4 bb = *(const float4*)(x1 + off);
            float4 c  = *(const float4*)(x2 + off);
            v.x = f2bf(w0*a.x + w1*bb.x + w2*c.x);
            v.y = f2bf(w0*a.y + w1*bb.y + w2*c.y);
            v.z = f2bf(w0*a.z + w1*bb.z + w2*c.z);
            v.w = f2bf(w0*a.w + w1*bb.w + w2*c.w);
        }
        *(ushort4*)&As[row * PITCH + c4] = v;
    }
    __syncthreads();                       // the ONLY barrier in the kernel

    f32x16 acc[2][2];
#pragma unroll
    for (int i = 0; i < 2; ++i)
#pragma unroll
        for (int j = 0; j < 2; ++j)
#pragma unroll
            for (int r = 0; r < 16; ++r)
                acc[i][j][r] = 0.f;

    // per-lane B base: row (co) = co_base + wc + lrow, k-element base = khalf*8
    const unsigned short* bbase =
        weff + (((size_t)s * KT * COUT) + co_base + wc + lrow) * CIN + khalf * 8;

    for (int dt = 0; dt < KT; ++dt) {
        const unsigned short* bdt = bbase + (size_t)dt * COUT * CIN;
        const int arow0 = wr + lrow + dt;
#pragma unroll
        for (int ci0 = 0; ci0 < CIN; ci0 += 32) {
            bf16x8 a[2][2], bf[2][2];
#pragma unroll
            for (int ks = 0; ks < 2; ++ks) {
#pragma unroll
                for (int j = 0; j < 2; ++j)
                    bf[j][ks] = *(const bf16x8*)&bdt[(size_t)(32*j) * CIN + ci0 + ks*16];
#pragma unroll
                for (int i = 0; i < 2; ++i)
                    a[i][ks] = *(const bf16x8*)&As[(arow0 + 32*i) * PITCH + ci0 + ks*16 + khalf*8];
            }
#pragma unroll
            for (int ks = 0; ks < 2; ++ks)
#pragma unroll
                for (int i = 0; i < 2; ++i)
#pragma unroll
                    for (int j = 0; j < 2; ++j)
                        acc[i][j] = __builtin_amdgcn_mfma_f32_32x32x16_bf16(
                            a[i][ks], bf[j][ks], acc[i][j], 0, 0, 0);
        }
    }

    // ---- epilogue: 32x32 C/D layout col=lane&31, row=(reg&3)+8*(reg>>2)+4*(lane>>5)
    float* obase = out + ((size_t)bsix * T_DIM + t0) * COUT + co_base;
#pragma unroll
    for (int i = 0; i < 2; ++i) {
#pragma unroll
        for (int j = 0; j < 2; ++j) {
            const int col = wc + 32*j + lrow;
#pragma unroll
            for (int r = 0; r < 16; ++r) {
                const int row = wr + 32*i + (r & 3) + 8*(r >> 2) + 4*khalf;
                obase[(size_t)row * COUT + col] = acc[i][j][r];
            }
        }
    }
}

// ---------------- host
extern "C" void kernel_launch(void* const* d_in, const int* in_sizes, int n_in,
                              void* d_out, int out_size, void* d_ws, size_t ws_size,
                              hipStream_t stream)
{
    const float* x      = (const float*)d_in[0];   // (8,8,4096,128) fp32
    const float* coeffs = (const float*)d_in[1];   // (5,128,256) fp32
    const float* cscale = (const float*)d_in[2];   // (3,) fp32
    float* out = (float*)d_out;                    // (8,8,4096,256) fp32
    unsigned short* weff = (unsigned short*)d_ws;  // bf16 [s][dt][co][ci] = 4.7 MB

    static const double SC[8] = {-1.5, -1.0, -0.5, 0.0, 0.5, 1.0, 1.5, 2.0};
    WtArgs wargs;
    for (int i = 0; i < S_DIM; ++i) {
        double alpha = SC[i];
        double scale = pow(2.0, alpha);
        double us    = pow(2.0, -alpha);
        for (int j = 0; j < KT; ++j) {
            double t = (j - 4.0) / 4.0;
            double u = t * us;
            double mask = (fabs(u) <= 1.0) ? 1.0 : 0.0;
            for (int k = 0; k < NK; ++k) {
                int freq = (k + 1) / 2;
                double arg = M_PI * (double)freq * u;
                double v = (k % 2 == 0) ? cos(arg) : sin(arg);
                wargs.wt[(i * KT + j) * NK + k] = (float)(mask * v * scale);
            }
        }
    }
    BsArgs bargs;
    for (int j = 0; j < 3; ++j) {
        double t = (double)(j - 1);
        for (int k = 0; k < 3; ++k) {
            int freq = (k + 1) / 2;
            double arg = M_PI * (double)freq * t;
            bargs.bs[j * 3 + k] = (float)((k % 2 == 0) ? cos(arg) : sin(arg));
        }
    }

    weights_kernel<<<dim3(S_DIM * KT, 4), dim3(256), 0, stream>>>(coeffs, weff, wargs);
    conv_kernel<<<dim3(T_DIM / BM, COUT / BN, B_DIM * S_DIM), dim3(256), 0, stream>>>(
        x, weff, cscale, out, bargs);
}